// Round 4
// baseline (859.344 us; speedup 1.0000x reference)
//
#include <hip/hip_runtime.h>

typedef unsigned short u16;
typedef unsigned long long u64;
typedef __attribute__((ext_vector_type(8))) short bf16x8;
typedef __attribute__((ext_vector_type(4))) float f32x4;

#define MFMA16(a, b, c) __builtin_amdgcn_mfma_f32_16x16x32_bf16((a), (b), (c), 0, 0, 0)

// ---- problem sizes ----
#define TT 128
#define BB 128
#define IN_ 512
#define HH 512
#define G4 2048   // 4*H
#define OUTD 512
#define TB 16384  // T*B

#define AEXLD(p) __hip_atomic_load((p), __ATOMIC_RELAXED, __HIP_MEMORY_SCOPE_AGENT)

__device__ __forceinline__ u16 f2bf(float f) {
    union { float f; unsigned u; } v; v.f = f;
    unsigned r = v.u + 0x7FFFu + ((v.u >> 16) & 1u);
    return (u16)(r >> 16);
}
__device__ __forceinline__ float bf2f(u16 h) {
    union { unsigned u; float f; } v; v.u = ((unsigned)h) << 16; return v.f;
}
__device__ __forceinline__ float sigmoid_f(float x) { return 1.f / (1.f + __expf(-x)); }
__device__ __forceinline__ float tanh_f(float x) {
    float e = __expf(2.f * x);
    return 1.f - 2.f / (e + 1.f);
}
// strip tags: u64 [tag|h1 : tag|h0] -> u32 (h1<<16 | h0)
__device__ __forceinline__ unsigned striptag(u64 v) {
    return (unsigned)(v & 0xffffu) | ((unsigned)(v >> 16) & 0xffff0000u);
}

// ---- fp32 -> bf16 convert (vectorized) ----
__global__ void cvt_kernel(const float* __restrict__ src, u16* __restrict__ dst, int n4) {
    int i = blockIdx.x * blockDim.x + threadIdx.x;
    int stride = gridDim.x * blockDim.x;
    for (; i < n4; i += stride) {
        float4 v = ((const float4*)src)[i];
        ushort4 o;
        o.x = f2bf(v.x); o.y = f2bf(v.y); o.z = f2bf(v.z); o.w = f2bf(v.w);
        ((ushort4*)dst)[i] = o;
    }
}

__global__ void bias_kernel(const float* __restrict__ bihf, const float* __restrict__ bhhf,
                            float* __restrict__ bf_, const float* __restrict__ bihb,
                            const float* __restrict__ bhhb, float* __restrict__ bb_, int n) {
    int i = blockIdx.x * blockDim.x + threadIdx.x;
    if (i < n) {
        bf_[i] = bihf[i] + bhhf[i];
        bb_[i] = bihb[i] + bhhb[i];
    }
}

// zero the 1 MB ping-pong h-exchange buffer (tags become 0 = invalid).
__global__ void zero_exch_kernel(uint4* __restrict__ p) {
    int i = blockIdx.x * blockDim.x + threadIdx.x;
    p[i] = uint4{0u, 0u, 0u, 0u};
}

// ---- generic 128x128-tile bf16 MFMA GEMM: C[M,N] = A[M,K] * W[N,K]^T + bias[N] ----
__global__ __launch_bounds__(256) void gemm_bias_kernel(
    const u16* __restrict__ A, const u16* __restrict__ W,
    const float* __restrict__ bias, void* __restrict__ Cout,
    int M, int N, int K, int out_is_bf16) {
    __shared__ __align__(16) u16 lA[128 * 72];
    __shared__ __align__(16) u16 lB[128 * 72];
    const int tid = threadIdx.x;
    const int m0 = blockIdx.x * 128;
    const int n0 = blockIdx.y * 128;
    const int wave = tid >> 6, lane = tid & 63;
    const int wm = wave >> 1, wn = wave & 1;
    const int lrow = lane & 15, lq = lane >> 4;

    f32x4 acc[4][4] = {};

    for (int kc = 0; kc < K; kc += 64) {
        #pragma unroll
        for (int i = 0; i < 4; ++i) {
            int c = i * 256 + tid;
            int row = c >> 3, off = c & 7;
            *(uint4*)(&lA[row * 72 + off * 8]) =
                *(const uint4*)(&A[(size_t)(m0 + row) * K + kc + off * 8]);
            *(uint4*)(&lB[row * 72 + off * 8]) =
                *(const uint4*)(&W[(size_t)(n0 + row) * K + kc + off * 8]);
        }
        __syncthreads();
        #pragma unroll
        for (int ks = 0; ks < 2; ++ks) {
            bf16x8 af[4], bfr[4];
            #pragma unroll
            for (int mf = 0; mf < 4; ++mf)
                af[mf] = *(const bf16x8*)(&lA[(wm * 64 + mf * 16 + lrow) * 72 + ks * 32 + lq * 8]);
            #pragma unroll
            for (int nf = 0; nf < 4; ++nf)
                bfr[nf] = *(const bf16x8*)(&lB[(wn * 64 + nf * 16 + lrow) * 72 + ks * 32 + lq * 8]);
            #pragma unroll
            for (int mf = 0; mf < 4; ++mf)
                #pragma unroll
                for (int nf = 0; nf < 4; ++nf)
                    acc[mf][nf] = MFMA16(af[mf], bfr[nf], acc[mf][nf]);
        }
        __syncthreads();
    }

    #pragma unroll
    for (int mf = 0; mf < 4; ++mf) {
        #pragma unroll
        for (int nf = 0; nf < 4; ++nf) {
            int row = m0 + wm * 64 + mf * 16 + lq * 4;
            int col = n0 + wn * 64 + nf * 16 + lrow;
            float bv = bias[col];
            f32x4 v = acc[mf][nf];
            #pragma unroll
            for (int r = 0; r < 4; ++r) {
                float val = v[r] + bv;
                if (out_is_bf16)
                    ((u16*)Cout)[(size_t)(row + r) * N + col] = f2bf(val);
                else
                    ((float*)Cout)[(size_t)(row + r) * N + col] = val;
            }
        }
    }
}

// ---- persistent fused recurrence: all 128 steps, both directions, one launch ----
// grid = 256 blocks: bx = dir*128 + bt*16 + jt. Block owns gates tile
// [16 batch x (4 gates x 32 j)]; W slice + c-state pinned in registers.
//
// K-partitioned waves: the recurrent GEMM's K dim (512 h features) is split into
// 16 chunks of 32; chunk kc is produced by group block jt=kc. Wave w consumes
// chunks {w, w+4, w+8, w+12}, computing PARTIAL sums for ALL 4 gates; the 4
// wave-partials are summed in the pointwise phase via sg[][]. Chunks are loaded
// DIRECTLY from the tagged exchange into MFMA A-fragments (lane (lrow,lq) loads
// row lrow, colpairs kc*16+lq*4+0..3 -> exactly the fragment) -- no LDS staging,
// and MFMA on ready chunks overlaps the laggard producer's arrival.
//
// Handoff: self-validating tagged u64 cells (tag16|h_bf16 per u32), relaxed
// agent-scope atomics only (no fences, no L2 writeback/inv). Ping-pong by step
// parity; tag check covers both halves of each u64 so torn loads only retry.
// ABA-safe: slot parity rewritten at s+2 requires the whole group past s+1.
__global__ __launch_bounds__(256, 1) void lstm_persist_kernel(
    const u16* __restrict__ xw_f, const u16* __restrict__ xw_b,
    const u16* __restrict__ whh_f, const u16* __restrict__ whh_b,
    u16* __restrict__ hcat, u64* __restrict__ exch) {
    const int bx = blockIdx.x;
    const int dir = bx >> 7;
    const int bt = (bx >> 4) & 7;
    const int jt = bx & 15;
    const u16* __restrict__ xw  = dir ? xw_b : xw_f;
    const u16* __restrict__ whh = dir ? whh_b : whh_f;
    const int b0 = bt * 16;
    const int j0 = jt * 32;

    __shared__ float sg[4][4][16][33];   // [wave][gate][b][j] partial sums

    const int tid = threadIdx.x;
    const int wave = tid >> 6, lane = tid & 63;
    const int lrow = lane & 15, lq = lane >> 4;

    // ---- preload W slice: wreg[gate][jh][ci] covers rows (g*512+j0+jh*16+lrow),
    //      k = (wave+ci*4)*32 + lq*8 .. +8  (128 VGPRs, pinned) ----
    bf16x8 wreg[4][2][4];
    #pragma unroll
    for (int g = 0; g < 4; ++g)
        #pragma unroll
        for (int jh = 0; jh < 2; ++jh)
            #pragma unroll
            for (int ci = 0; ci < 4; ++ci)
                wreg[g][jh][ci] = *(const bf16x8*)
                    (&whh[(size_t)(g * HH + j0 + jh * 16 + lrow) * HH +
                          (wave + ci * 4) * 32 + lq * 8]);
    #pragma unroll
    for (int g = 0; g < 4; ++g)
        #pragma unroll
        for (int jh = 0; jh < 2; ++jh)
            #pragma unroll
            for (int ci = 0; ci < 4; ++ci)
                asm volatile("" : "+v"(wreg[g][jh][ci]));

    // pointwise cell ownership: thread -> (batch row bl, adjacent cols jj, jj+1)
    const int bl = tid >> 4;
    const int jj = (tid & 15) * 2;
    float cr0 = 0.f, cr1 = 0.f;

    // producer exchange slot (u64 = cell pair)
    const size_t my_ex = ((size_t)dir * BB + b0 + bl) * 256 + (j0 >> 1) + (tid & 15);
    // consumer bases per parity: row = b0+lrow, + lane's lq*4 colpair offset
    const u64* exb0 = exch + ((size_t)(0 * 2 + dir) * BB + b0 + lrow) * 256 + lq * 4;
    const u64* exb1 = exch + ((size_t)(1 * 2 + dir) * BB + b0 + lrow) * 256 + lq * 4;

    const u64 TMASK = 0xFFFF0000FFFF0000ull;

    for (int s = 0; s < TT; ++s) {
        const int t = dir ? (TT - 1 - s) : s;

        // prefetch xw for this thread's 2 cells (4 gates, u32 each)
        const u16* xrow = xw + ((size_t)t * BB + b0 + bl) * G4 + j0 + jj;
        unsigned xg[4];
        #pragma unroll
        for (int g = 0; g < 4; ++g)
            xg[g] = *(const unsigned*)(xrow + (size_t)g * HH);

        f32x4 acc[4][2] = {};
        if (s > 0) {
            const u64* eb = ((s - 1) & 1) ? exb1 : exb0;
            const u64 expect = ((u64)(unsigned)s << 48) | ((u64)(unsigned)s << 16);

            // speculative volley: issue all 16 loads (4 chunks x 4 u64) at once
            u64 v[4][4];
            #pragma unroll
            for (int ci = 0; ci < 4; ++ci) {
                const u64* cp = eb + (size_t)(wave + ci * 4) * 16;
                #pragma unroll
                for (int k = 0; k < 4; ++k)
                    v[ci][k] = AEXLD(cp + k);
            }
            // per-chunk: fix up if stale, then MFMA (overlaps other arrivals)
            #pragma unroll
            for (int ci = 0; ci < 4; ++ci) {
                const u64* cp = eb + (size_t)(wave + ci * 4) * 16;
                for (;;) {
                    bool ok = ((v[ci][0] & TMASK) == expect) &
                              ((v[ci][1] & TMASK) == expect) &
                              ((v[ci][2] & TMASK) == expect) &
                              ((v[ci][3] & TMASK) == expect);
                    if (ok) break;
                    #pragma unroll
                    for (int k = 0; k < 4; ++k)
                        v[ci][k] = AEXLD(cp + k);
                }
                union { unsigned u[4]; bf16x8 b8; } ua;
                #pragma unroll
                for (int k = 0; k < 4; ++k)
                    ua.u[k] = striptag(v[ci][k]);
                bf16x8 a = ua.b8;
                #pragma unroll
                for (int g = 0; g < 4; ++g) {
                    acc[g][0] = MFMA16(a, wreg[g][0][ci], acc[g][0]);
                    acc[g][1] = MFMA16(a, wreg[g][1][ci], acc[g][1]);
                }
            }
        }

        __syncthreads();   // WAR: previous pointwise done reading sg
        // partials -> LDS (D layout: m = lq*4+r batch-local, n = jh*16+lrow)
        #pragma unroll
        for (int g = 0; g < 4; ++g)
            #pragma unroll
            for (int jh = 0; jh < 2; ++jh)
                #pragma unroll
                for (int r = 0; r < 4; ++r)
                    sg[wave][g][lq * 4 + r][jh * 16 + lrow] = acc[g][jh][r];
        __syncthreads();   // sg ready

        // pointwise: sum 4 wave-partials, add xw, update c, publish h
        float gv0[4], gv1[4];
        #pragma unroll
        for (int g = 0; g < 4; ++g) {
            gv0[g] = sg[0][g][bl][jj] + sg[1][g][bl][jj] +
                     sg[2][g][bl][jj] + sg[3][g][bl][jj] +
                     bf2f((u16)(xg[g] & 0xffffu));
            gv1[g] = sg[0][g][bl][jj + 1] + sg[1][g][bl][jj + 1] +
                     sg[2][g][bl][jj + 1] + sg[3][g][bl][jj + 1] +
                     bf2f((u16)(xg[g] >> 16));
        }
        float c0 = sigmoid_f(gv0[1]) * cr0 + sigmoid_f(gv0[0]) * tanh_f(gv0[2]);
        float c1 = sigmoid_f(gv1[1]) * cr1 + sigmoid_f(gv1[0]) * tanh_f(gv1[2]);
        cr0 = c0; cr1 = c1;
        float h0 = sigmoid_f(gv0[3]) * tanh_f(c0);
        float h1 = sigmoid_f(gv1[3]) * tanh_f(c1);

        // publish: ONE tagged u64 (self-validating, relaxed agent scope)
        unsigned hb0 = (unsigned)f2bf(h0), hb1 = (unsigned)f2bf(h1);
        unsigned tagv = (unsigned)(s + 1) << 16;
        u64 pv = (u64)(tagv | hb0) | ((u64)(tagv | hb1) << 32);
        __hip_atomic_store(exch + (size_t)((s & 1) * 2) * BB * 256 + my_ex, pv,
                           __ATOMIC_RELAXED, __HIP_MEMORY_SCOPE_AGENT);

        // hcat for phase 3 (normal cached store; off the critical path)
        *(unsigned*)(hcat + ((size_t)t * BB + b0 + bl) * (2 * HH) + dir * HH + j0 + jj) =
            hb0 | (hb1 << 16);
    }
}

// ---- workspace layout (bytes) ----
#define OFF_XBF    ((size_t)0)
#define OFF_WIHF   (OFF_XBF  + (size_t)TB * IN_ * 2)
#define OFF_WIHB   (OFF_WIHF + (size_t)G4 * IN_ * 2)
#define OFF_WHHF   (OFF_WIHB + (size_t)G4 * IN_ * 2)
#define OFF_WHHB   (OFF_WHHF + (size_t)G4 * HH * 2)
#define OFF_WLIN   (OFF_WHHB + (size_t)G4 * HH * 2)
#define OFF_BIASF  (OFF_WLIN + (size_t)OUTD * 2 * HH * 2)
#define OFF_BIASB  (OFF_BIASF + (size_t)G4 * 4)
#define OFF_XWF    (OFF_BIASB + (size_t)G4 * 4)
#define OFF_XWB    (OFF_XWF  + (size_t)TB * G4 * 2)
#define OFF_HCAT   (OFF_XWB  + (size_t)TB * G4 * 2)
#define OFF_EXCH   (OFF_HCAT + (size_t)TB * 2 * HH * 2)   // ping-pong tagged h: 1 MB
#define WS_NEED    (OFF_EXCH + (size_t)2 * 2 * BB * HH * 4)

extern "C" void kernel_launch(void* const* d_in, const int* in_sizes, int n_in,
                              void* d_out, int out_size, void* d_ws, size_t ws_size,
                              hipStream_t stream) {
    (void)in_sizes; (void)n_in; (void)out_size;
    if (ws_size < WS_NEED) return;

    const float* x    = (const float*)d_in[0];
    const float* Wihf = (const float*)d_in[1];
    const float* Whhf = (const float*)d_in[2];
    const float* bihf = (const float*)d_in[3];
    const float* bhhf = (const float*)d_in[4];
    const float* Wihb = (const float*)d_in[5];
    const float* Whhb = (const float*)d_in[6];
    const float* bihb = (const float*)d_in[7];
    const float* bhhb = (const float*)d_in[8];
    const float* Wlin = (const float*)d_in[9];
    const float* blin = (const float*)d_in[10];
    float* out = (float*)d_out;

    char* ws = (char*)d_ws;
    u16* x_bf    = (u16*)(ws + OFF_XBF);
    u16* wihf_bf = (u16*)(ws + OFF_WIHF);
    u16* wihb_bf = (u16*)(ws + OFF_WIHB);
    u16* whhf_bf = (u16*)(ws + OFF_WHHF);
    u16* whhb_bf = (u16*)(ws + OFF_WHHB);
    u16* wlin_bf = (u16*)(ws + OFF_WLIN);
    float* bias_f = (float*)(ws + OFF_BIASF);
    float* bias_b = (float*)(ws + OFF_BIASB);
    u16* xw_f = (u16*)(ws + OFF_XWF);
    u16* xw_b = (u16*)(ws + OFF_XWB);
    u16* hcat = (u16*)(ws + OFF_HCAT);
    u64* exch = (u64*)(ws + OFF_EXCH);

    // prep: convert to bf16, sum biases, invalidate exchange tags
    cvt_kernel<<<2048, 256, 0, stream>>>(x, x_bf, (TB * IN_) / 4);
    cvt_kernel<<<512, 256, 0, stream>>>(Wihf, wihf_bf, (G4 * IN_) / 4);
    cvt_kernel<<<512, 256, 0, stream>>>(Wihb, wihb_bf, (G4 * IN_) / 4);
    cvt_kernel<<<512, 256, 0, stream>>>(Whhf, whhf_bf, (G4 * HH) / 4);
    cvt_kernel<<<512, 256, 0, stream>>>(Whhb, whhb_bf, (G4 * HH) / 4);
    cvt_kernel<<<512, 256, 0, stream>>>(Wlin, wlin_bf, (OUTD * 2 * HH) / 4);
    bias_kernel<<<8, 256, 0, stream>>>(bihf, bhhf, bias_f, bihb, bhhb, bias_b, G4);
    zero_exch_kernel<<<256, 256, 0, stream>>>((uint4*)exch);

    // phase 1: xw = x @ W_ih^T + (b_ih + b_hh), bf16 out
    gemm_bias_kernel<<<dim3(TB / 128, G4 / 128), 256, 0, stream>>>(
        x_bf, wihf_bf, bias_f, xw_f, TB, G4, IN_, 1);
    gemm_bias_kernel<<<dim3(TB / 128, G4 / 128), 256, 0, stream>>>(
        x_bf, wihb_bf, bias_b, xw_b, TB, G4, IN_, 1);

    // phase 2: one persistent kernel for all 128 recurrent steps, both dirs
    {
        void* args[] = { (void*)&xw_f, (void*)&xw_b, (void*)&whhf_bf, (void*)&whhb_bf,
                         (void*)&hcat, (void*)&exch };
        hipError_t e = hipLaunchCooperativeKernel(
            (const void*)lstm_persist_kernel, dim3(256), dim3(256), args, 0, stream);
        if (e != hipSuccess) {
            // fallback: plain launch. 256 blocks <= 256 CUs with
            // __launch_bounds__(256,1) -> co-resident by capacity.
            lstm_persist_kernel<<<256, 256, 0, stream>>>(xw_f, xw_b, whhf_bf, whhb_bf,
                                                         hcat, exch);
        }
    }

    // phase 3: out = hcat @ W_lin^T + b_lin, fp32 out
    gemm_bias_kernel<<<dim3(TB / 128, OUTD / 128), 256, 0, stream>>>(
        hcat, wlin_bf, blin, out, TB, OUTD, 2 * HH, 0);
}

// Round 5
// 693.135 us; speedup vs baseline: 1.2398x; 1.2398x over previous
//
#include <hip/hip_runtime.h>

typedef unsigned short u16;
typedef unsigned long long u64;
typedef __attribute__((ext_vector_type(8))) short bf16x8;
typedef __attribute__((ext_vector_type(4))) float f32x4;

#define MFMA16(a, b, c) __builtin_amdgcn_mfma_f32_16x16x32_bf16((a), (b), (c), 0, 0, 0)

// ---- problem sizes ----
#define TT 128
#define BB 128
#define IN_ 512
#define HH 512
#define G4 2048   // 4*H
#define OUTD 512
#define TB 16384  // T*B

#define AEXLD(p) __hip_atomic_load((p), __ATOMIC_RELAXED, __HIP_MEMORY_SCOPE_AGENT)

__device__ __forceinline__ u16 f2bf(float f) {
    union { float f; unsigned u; } v; v.f = f;
    unsigned r = v.u + 0x7FFFu + ((v.u >> 16) & 1u);
    return (u16)(r >> 16);
}
__device__ __forceinline__ float bf2f(u16 h) {
    union { unsigned u; float f; } v; v.u = ((unsigned)h) << 16; return v.f;
}
__device__ __forceinline__ float sigmoid_f(float x) { return 1.f / (1.f + __expf(-x)); }
__device__ __forceinline__ float tanh_f(float x) {
    float e = __expf(2.f * x);
    return 1.f - 2.f / (e + 1.f);
}

// ---- async global->LDS, 16B per lane. LDS dest = wave-uniform base + lane*16
// (m104/m108 semantics: LDS must be LINEAR, source gaddr is per-lane). ----
typedef unsigned __attribute__((address_space(1))) guint;
typedef unsigned __attribute__((address_space(3))) luint;
__device__ __forceinline__ void gll16(const u16* g, u16* l) {
    __builtin_amdgcn_global_load_lds((guint*)(void*)g, (luint*)(void*)l, 16, 0, 0);
}

// ---- fused prep: all bf16 converts + stacked bias + exchange-tag zero ----
// wih_cat rows 0..2047 = W_ih_f, 2048..4095 = W_ih_b (for merged phase-1 GEMM).
__global__ void prep_kernel(
    const float* __restrict__ x,
    const float* __restrict__ Wihf, const float* __restrict__ Wihb,
    const float* __restrict__ Whhf, const float* __restrict__ Whhb,
    const float* __restrict__ Wlin,
    const float* __restrict__ bihf, const float* __restrict__ bhhf,
    const float* __restrict__ bihb, const float* __restrict__ bhhb,
    u16* __restrict__ x_bf, u16* __restrict__ wih_cat,
    u16* __restrict__ whhf_bf, u16* __restrict__ whhb_bf,
    u16* __restrict__ wlin_bf, float* __restrict__ bias_cat,
    uint4* __restrict__ exch) {
    const int i0 = blockIdx.x * blockDim.x + threadIdx.x;
    const int stride = gridDim.x * blockDim.x;
    #define CVT4(SRC, DST, N4, DOFF)                                        \
        for (int i = i0; i < (N4); i += stride) {                           \
            float4 v = ((const float4*)(SRC))[i];                           \
            ushort4 o;                                                      \
            o.x = f2bf(v.x); o.y = f2bf(v.y);                               \
            o.z = f2bf(v.z); o.w = f2bf(v.w);                               \
            ((ushort4*)(DST))[(DOFF) + i] = o;                              \
        }
    CVT4(x, x_bf, (TB * IN_) / 4, 0)
    CVT4(Wihf, wih_cat, (G4 * IN_) / 4, 0)
    CVT4(Wihb, wih_cat, (G4 * IN_) / 4, (G4 * IN_) / 4)
    CVT4(Whhf, whhf_bf, (G4 * HH) / 4, 0)
    CVT4(Whhb, whhb_bf, (G4 * HH) / 4, 0)
    CVT4(Wlin, wlin_bf, (OUTD * 2 * HH) / 4, 0)
    #undef CVT4
    for (int i = i0; i < G4; i += stride) {
        bias_cat[i]      = bihf[i] + bhhf[i];
        bias_cat[G4 + i] = bihb[i] + bhhb[i];
    }
    for (int i = i0; i < 65536; i += stride)   // 1 MB exchange: tags -> 0 (invalid)
        exch[i] = uint4{0u, 0u, 0u, 0u};
}

// ---- generic 128x128-tile bf16 MFMA GEMM: C[M,N] = A[M,K] * W[N,K]^T + bias[N]
// m97-style staging: global_load_lds width 16 into LINEAR [128][64] LDS tiles. ----
__global__ __launch_bounds__(256) void gemm_bias_kernel(
    const u16* __restrict__ A, const u16* __restrict__ W,
    const float* __restrict__ bias, void* __restrict__ Cout,
    int M, int N, int K, int out_is_bf16) {
    __shared__ __align__(16) u16 lA[128 * 64];   // linear, stride 64 (required by gll16)
    __shared__ __align__(16) u16 lB[128 * 64];
    const int tid = threadIdx.x;
    const int m0 = blockIdx.x * 128;
    const int n0 = blockIdx.y * 128;
    const int wave = tid >> 6, lane = tid & 63;
    const int wm = wave >> 1, wn = wave & 1;
    const int lrow = lane & 15, lq = lane >> 4;
    const int srow = lane >> 3, soff = (lane & 7) * 8;   // staging: 8 rows/wave-call

    f32x4 acc[4][4] = {};

    for (int kc = 0; kc < K; kc += 64) {
        // stage A,B tiles: 16 wave-calls each of 1KB (8 rows x 128B), linear LDS
        #pragma unroll
        for (int i = 0; i < 4; ++i) {
            int chunk = wave + i * 4;          // 0..15
            int row = chunk * 8 + srow;
            gll16(&A[(size_t)(m0 + row) * K + kc + soff], &lA[chunk * 512]);
            gll16(&W[(size_t)(n0 + row) * K + kc + soff], &lB[chunk * 512]);
        }
        __syncthreads();   // compiler drains vmcnt before the barrier
        #pragma unroll
        for (int ks = 0; ks < 2; ++ks) {
            bf16x8 af[4], bfr[4];
            #pragma unroll
            for (int mf = 0; mf < 4; ++mf)
                af[mf] = *(const bf16x8*)(&lA[(wm * 64 + mf * 16 + lrow) * 64 + ks * 32 + lq * 8]);
            #pragma unroll
            for (int nf = 0; nf < 4; ++nf)
                bfr[nf] = *(const bf16x8*)(&lB[(wn * 64 + nf * 16 + lrow) * 64 + ks * 32 + lq * 8]);
            #pragma unroll
            for (int mf = 0; mf < 4; ++mf)
                #pragma unroll
                for (int nf = 0; nf < 4; ++nf)
                    acc[mf][nf] = MFMA16(af[mf], bfr[nf], acc[mf][nf]);
        }
        __syncthreads();
    }

    #pragma unroll
    for (int mf = 0; mf < 4; ++mf) {
        #pragma unroll
        for (int nf = 0; nf < 4; ++nf) {
            int row = m0 + wm * 64 + mf * 16 + lq * 4;
            int col = n0 + wn * 64 + nf * 16 + lrow;
            float bv = bias[col];
            f32x4 v = acc[mf][nf];
            #pragma unroll
            for (int r = 0; r < 4; ++r) {
                float val = v[r] + bv;
                if (out_is_bf16)
                    ((u16*)Cout)[(size_t)(row + r) * N + col] = f2bf(val);
                else
                    ((float*)Cout)[(size_t)(row + r) * N + col] = val;
            }
        }
    }
}

// ---- persistent fused recurrence (r3 structure, verified 406 us) ----
// grid = 256 blocks: bx = dir*128 + bt*16 + jt. Block owns gates tile
// [16 batch x (4 gates x 32 j)]; W_hh slice + c-state pinned in registers.
// Handoff: self-validating tagged u64 cells (tag16|h_bf16 per u32), relaxed
// agent-scope atomics only; coalesced 16-u64 volley into LDS; ping-pong by
// step parity; tag mismatch only ever causes a retry (ABA-safe, see r3).
__global__ __launch_bounds__(256, 1) void lstm_persist_kernel(
    const u16* __restrict__ xw, const u16* __restrict__ whh_f,
    const u16* __restrict__ whh_b, u16* __restrict__ hcat,
    u64* __restrict__ exch) {
    const int bx = blockIdx.x;
    const int dir = bx >> 7;
    const int bt = (bx >> 4) & 7;
    const int jt = bx & 15;
    const u16* __restrict__ whh = dir ? whh_b : whh_f;
    const int b0 = bt * 16;
    const int j0 = jt * 32;

    __shared__ __align__(16) u16 lh[16 * 520];   // h_prev tile [16 x 512], stride 520
    __shared__ float sgate[4][16][33];           // gate exchange [gate][b][j]

    const int tid = threadIdx.x;
    const int wave = tid >> 6, lane = tid & 63;
    const int lrow = lane & 15, lq = lane >> 4;

    // ---- preload this wave's W_hh slice (gate `wave`, 32 rows x K=512) into regs ----
    const u16* wrow = whh + ((size_t)wave * HH + j0) * HH;
    bf16x8 w0[16], w1[16];
    #pragma unroll
    for (int kc = 0; kc < 16; ++kc) {
        w0[kc] = *(const bf16x8*)(&wrow[(size_t)lrow * HH + kc * 32 + lq * 8]);
        w1[kc] = *(const bf16x8*)(&wrow[(size_t)(16 + lrow) * HH + kc * 32 + lq * 8]);
    }
    #pragma unroll
    for (int kc = 0; kc < 16; ++kc)
        asm volatile("" : "+v"(w0[kc]), "+v"(w1[kc]));

    // pointwise cell ownership: thread -> (batch row bl, adjacent cols jj, jj+1)
    const int bl = tid >> 4;
    const int jj = (tid & 15) * 2;
    float cr0 = 0.f, cr1 = 0.f;

    // producer-side exchange slot (u64 = adjacent cell pair)
    const size_t my_ex = ((size_t)dir * BB + b0 + bl) * 256 + (j0 >> 1) + (tid & 15);

    for (int s = 0; s < TT; ++s) {
        const int t = dir ? (TT - 1 - s) : s;

        // prefetch xw for this thread's 2 cells (4 gates, u32 each) before the wait
        const u16* xrow = xw + ((size_t)t * BB + b0 + bl) * (2 * G4) + dir * G4 + j0 + jj;
        unsigned xg[4];
        #pragma unroll
        for (int g = 0; g < 4; ++g)
            xg[g] = *(const unsigned*)(xrow + (size_t)g * HH);

        f32x4 acc0 = {}, acc1 = {}, acc0b = {}, acc1b = {};
        if (s > 0) {
            // ---- single-RT handoff: load 16 tagged u64s (coalesced), retry until valid ----
            const int p = (s - 1) & 1;
            const u64* ex = exch + ((size_t)(p * 2 + dir) * BB + b0) * 256 + tid;
            const u64 expect = ((u64)(unsigned)s << 48) | ((u64)(unsigned)s << 16);
            u64 v[16];
            for (;;) {
                #pragma unroll
                for (int i = 0; i < 16; ++i)
                    v[i] = AEXLD(ex + (size_t)i * 256);
                bool ok = true;
                #pragma unroll
                for (int i = 0; i < 16; ++i)
                    ok &= ((v[i] & 0xFFFF0000FFFF0000ull) == expect);
                if (ok) break;
            }
            // unpack to lh: cells (2*tid, 2*tid+1) of row i -> packed u32
            #pragma unroll
            for (int i = 0; i < 16; ++i)
                *(unsigned*)(&lh[i * 520 + tid * 2]) =
                    (unsigned)(v[i] & 0xffffu) | (unsigned)((v[i] >> 16) & 0xffff0000u);
            __syncthreads();   // bar A: lh ready

            #pragma unroll
            for (int kc = 0; kc < 16; kc += 2) {
                bf16x8 a0 = *(const bf16x8*)(&lh[lrow * 520 + kc * 32 + lq * 8]);
                bf16x8 a1 = *(const bf16x8*)(&lh[lrow * 520 + (kc + 1) * 32 + lq * 8]);
                acc0  = MFMA16(a0, w0[kc], acc0);
                acc1  = MFMA16(a0, w1[kc], acc1);
                acc0b = MFMA16(a1, w0[kc + 1], acc0b);
                acc1b = MFMA16(a1, w1[kc + 1], acc1b);
            }
            acc0 += acc0b;
            acc1 += acc1b;
        }

        // gates -> LDS (D layout: m = lq*4+r batch-local, n in {lrow, 16+lrow})
        #pragma unroll
        for (int r = 0; r < 4; ++r) {
            sgate[wave][lq * 4 + r][lrow]      = acc0[r];
            sgate[wave][lq * 4 + r][16 + lrow] = acc1[r];
        }
        __syncthreads();   // bar B: gates ready (also protects lh vs next fill)

        // pointwise: 2 adjacent cells per thread, c in registers
        float gi0 = sgate[0][bl][jj]     + bf2f((u16)(xg[0] & 0xffffu));
        float gf0 = sgate[1][bl][jj]     + bf2f((u16)(xg[1] & 0xffffu));
        float gg0 = sgate[2][bl][jj]     + bf2f((u16)(xg[2] & 0xffffu));
        float go0 = sgate[3][bl][jj]     + bf2f((u16)(xg[3] & 0xffffu));
        float gi1 = sgate[0][bl][jj + 1] + bf2f((u16)(xg[0] >> 16));
        float gf1 = sgate[1][bl][jj + 1] + bf2f((u16)(xg[1] >> 16));
        float gg1 = sgate[2][bl][jj + 1] + bf2f((u16)(xg[2] >> 16));
        float go1 = sgate[3][bl][jj + 1] + bf2f((u16)(xg[3] >> 16));

        float c0 = sigmoid_f(gf0) * cr0 + sigmoid_f(gi0) * tanh_f(gg0);
        float c1 = sigmoid_f(gf1) * cr1 + sigmoid_f(gi1) * tanh_f(gg1);
        cr0 = c0; cr1 = c1;
        float h0 = sigmoid_f(go0) * tanh_f(c0);
        float h1 = sigmoid_f(go1) * tanh_f(c1);

        // publish: ONE tagged u64 (self-validating, relaxed agent scope)
        unsigned hb0 = (unsigned)f2bf(h0), hb1 = (unsigned)f2bf(h1);
        unsigned tagv = (unsigned)(s + 1) << 16;
        u64 pv = (u64)(tagv | hb0) | ((u64)(tagv | hb1) << 32);
        __hip_atomic_store(exch + (size_t)((s & 1) * 2) * BB * 256 + my_ex, pv,
                           __ATOMIC_RELAXED, __HIP_MEMORY_SCOPE_AGENT);

        // hcat for phase 3 (normal cached store; off the critical path)
        *(unsigned*)(hcat + ((size_t)t * BB + b0 + bl) * (2 * HH) + dir * HH + j0 + jj) =
            hb0 | (hb1 << 16);
    }
}

// ---- workspace layout (bytes) ----
#define OFF_XBF    ((size_t)0)                             // 16,777,216
#define OFF_WIH    (OFF_XBF  + (size_t)TB * IN_ * 2)       // stacked W_ih: 4,194,304
#define OFF_WHHF   (OFF_WIH  + (size_t)2 * G4 * IN_ * 2)
#define OFF_WHHB   (OFF_WHHF + (size_t)G4 * HH * 2)
#define OFF_WLIN   (OFF_WHHB + (size_t)G4 * HH * 2)
#define OFF_BIAS   (OFF_WLIN + (size_t)OUTD * 2 * HH * 2)  // stacked bias: 16,384
#define OFF_XW     (OFF_BIAS + (size_t)2 * G4 * 4)         // [TB][4096]: 134,217,728
#define OFF_HCAT   (OFF_XW   + (size_t)TB * 2 * G4 * 2)    // 33,554,432
#define OFF_EXCH   (OFF_HCAT + (size_t)TB * 2 * HH * 2)    // tagged ping-pong h: 1 MB
#define WS_NEED    (OFF_EXCH + (size_t)2 * 2 * BB * HH * 4)

extern "C" void kernel_launch(void* const* d_in, const int* in_sizes, int n_in,
                              void* d_out, int out_size, void* d_ws, size_t ws_size,
                              hipStream_t stream) {
    (void)in_sizes; (void)n_in; (void)out_size;
    if (ws_size < WS_NEED) return;

    const float* x    = (const float*)d_in[0];
    const float* Wihf = (const float*)d_in[1];
    const float* Whhf = (const float*)d_in[2];
    const float* bihf = (const float*)d_in[3];
    const float* bhhf = (const float*)d_in[4];
    const float* Wihb = (const float*)d_in[5];
    const float* Whhb = (const float*)d_in[6];
    const float* bihb = (const float*)d_in[7];
    const float* bhhb = (const float*)d_in[8];
    const float* Wlin = (const float*)d_in[9];
    const float* blin = (const float*)d_in[10];
    float* out = (float*)d_out;

    char* ws = (char*)d_ws;
    u16* x_bf     = (u16*)(ws + OFF_XBF);
    u16* wih_cat  = (u16*)(ws + OFF_WIH);
    u16* whhf_bf  = (u16*)(ws + OFF_WHHF);
    u16* whhb_bf  = (u16*)(ws + OFF_WHHB);
    u16* wlin_bf  = (u16*)(ws + OFF_WLIN);
    float* bias_cat = (float*)(ws + OFF_BIAS);
    u16* xw   = (u16*)(ws + OFF_XW);
    u16* hcat = (u16*)(ws + OFF_HCAT);
    u64* exch = (u64*)(ws + OFF_EXCH);

    // prep: all converts + stacked bias + exchange-tag zero, ONE launch
    prep_kernel<<<1024, 256, 0, stream>>>(x, Wihf, Wihb, Whhf, Whhb, Wlin,
                                          bihf, bhhf, bihb, bhhb,
                                          x_bf, wih_cat, whhf_bf, whhb_bf, wlin_bf,
                                          bias_cat, (uint4*)exch);

    // phase 1: xw = x @ [W_ih_f; W_ih_b]^T + bias_cat, bf16 out, ONE GEMM (N=4096)
    gemm_bias_kernel<<<dim3(TB / 128, (2 * G4) / 128), 256, 0, stream>>>(
        x_bf, wih_cat, bias_cat, xw, TB, 2 * G4, IN_, 1);

    // phase 2: one persistent kernel for all 128 recurrent steps, both dirs
    {
        void* args[] = { (void*)&xw, (void*)&whhf_bf, (void*)&whhb_bf,
                         (void*)&hcat, (void*)&exch };
        hipError_t e = hipLaunchCooperativeKernel(
            (const void*)lstm_persist_kernel, dim3(256), dim3(256), args, 0, stream);
        if (e != hipSuccess) {
            // fallback: plain launch. 256 blocks <= 256 CUs with
            // __launch_bounds__(256,1) -> co-resident by capacity.
            lstm_persist_kernel<<<256, 256, 0, stream>>>(xw, whhf_bf, whhb_bf,
                                                         hcat, exch);
        }
    }

    // phase 3: out = hcat @ W_lin^T + b_lin, fp32 out
    gemm_bias_kernel<<<dim3(TB / 128, OUTD / 128), 256, 0, stream>>>(
        hcat, wlin_bf, blin, out, TB, OUTD, 2 * HH, 0);
}